// Round 2
// baseline (312.791 us; speedup 1.0000x reference)
//
#include <hip/hip_runtime.h>

#define V 5003
#define BB 64
#define SS 200
#define DD 128
#define TAU 0.07f
#define LOG2E 1.4426950408889634f
#define LN2 0.6931471805599453f
#define SHIFT 8.0f   // lse = SHIFT + log(sum exp(x - SHIFT)); exact, overflow-proof for |x|<80

// ws layout: [0]=focal_sum [1]=valid_count [2]=contrastive_sum [3]=pairs

__global__ void init_ws_kernel(float* ws) {
    if (threadIdx.x < 4) ws[threadIdx.x] = 0.0f;
}

__global__ __launch_bounds__(256) void fused_loss_kernel(
    const float* __restrict__ logits,   // [64,128,5003]
    const int*   __restrict__ targets,  // [64,128]
    const int*   __restrict__ mmask,    // [64,128]
    const float* __restrict__ emb,      // [64,200,128]
    const int*   __restrict__ pids,     // [64,200]
    const int*   __restrict__ amask,    // [64,200]
    float* __restrict__ ws)
{
    const int tid  = threadIdx.x;
    const int lane = tid & 63;
    const int wave = tid >> 6;

    __shared__ float fl_sh[4];
    __shared__ int   vc_sh[4];
    __shared__ __align__(16) float anchors[8][DD];
    __shared__ float possim[8];
    __shared__ unsigned char validb[SS];
    __shared__ short poslist[16];
    __shared__ int   n_sh;
    __shared__ int   nanch_sh;
    __shared__ float red[4][8];
    __shared__ float contrib_sh[8];

    if (blockIdx.x < 2048) {
        // ================= FOCAL: one wave per row, shifted sum-exp =================
        const int r = blockIdx.x * 4 + wave;
        const float* row = logits + (size_t)r * V;

        // alignment peel: row starts at element r*5003; (r*5003)%4 == (r*3)%4
        const int p = (4 - ((r * 3) & 3)) & 3;     // scalars before 16B alignment
        // (V - p) / 4 == 1250 for all p in {0..3}; tail t = 3 - p
        const int t = 3 - p;

        const float4* row4 = (const float4*)(row + p);
        const float C = -SHIFT * LOG2E;

        float s0 = 0.f, s1 = 0.f, s2 = 0.f, s3 = 0.f;

        // 1250 float4 per row: 19 full wave-iterations + 34-lane partial
        int i = lane;
        #pragma unroll 4
        for (int it = 0; it < 19; ++it, i += 64) {
            float4 x = row4[i];
            s0 += exp2f(fmaf(x.x, LOG2E, C));
            s1 += exp2f(fmaf(x.y, LOG2E, C));
            s2 += exp2f(fmaf(x.z, LOG2E, C));
            s3 += exp2f(fmaf(x.w, LOG2E, C));
        }
        if (i < 1250) {                 // lanes 0..33
            float4 x = row4[i];
            s0 += exp2f(fmaf(x.x, LOG2E, C));
            s1 += exp2f(fmaf(x.y, LOG2E, C));
            s2 += exp2f(fmaf(x.z, LOG2E, C));
            s3 += exp2f(fmaf(x.w, LOG2E, C));
        }
        if (lane < p)                   // head scalars
            s0 += exp2f(fmaf(row[lane], LOG2E, C));
        if (lane < t)                   // tail scalars
            s0 += exp2f(fmaf(row[p + 5000 + lane], LOG2E, C));

        float s = (s0 + s1) + (s2 + s3);
        for (int off = 32; off; off >>= 1)
            s += __shfl_xor(s, off, 64);

        if (lane == 0) {
            int tg  = targets[r];
            int mk  = mmask[r];
            bool valid = (tg != -100) && (mk == 1);
            int tc = tg < 0 ? 0 : tg;
            float xt  = row[tc];
            float lse = SHIFT + log2f(s) * LN2;
            float lp  = xt - lse;                // log p_t  (<= 0)
            float pt  = exp2f(lp * LOG2E);
            float om  = 1.0f - pt;
            fl_sh[wave] = valid ? (om * om * (-lp)) : 0.0f;
            vc_sh[wave] = valid ? 1 : 0;
        }
        __syncthreads();
        if (tid == 0) {
            float fs = fl_sh[0] + fl_sh[1] + fl_sh[2] + fl_sh[3];
            int   vc = vc_sh[0] + vc_sh[1] + vc_sh[2] + vc_sh[3];
            atomicAdd(&ws[0], fs);
            atomicAdd(&ws[1], (float)vc);
        }
    } else {
        // ================= CONTRASTIVE: one block per batch =================
        const int b = blockIdx.x - 2048;

        if (tid == 0) n_sh = 0;
        __syncthreads();

        if (tid < SS) {
            int idx = b * SS + tid;
            bool v = (amask[idx] == 1) && (pids[idx] > 0);
            validb[tid] = v ? 1 : 0;
            if (v) atomicAdd(&n_sh, 1);
        }
        __syncthreads();

        if (tid == 0) {
            int cnt = 0;
            for (int s = 0; s < SS && cnt < 16; ++s)
                if (validb[s]) poslist[cnt++] = (short)s;
            for (; cnt < 16; ++cnt) poslist[cnt] = (short)(SS - 1);
            int n  = n_sh;
            int na = n / 2;
            if (na > 8) na = 8;
            nanch_sh = na;
        }
        __syncthreads();
        const int n_anch = nanch_sh;

        const float2* embb = (const float2*)(emb + (size_t)b * SS * DD);
        for (int jj = 0; jj < 2; ++jj) {
            int j = wave + jj * 4;
            if (j < n_anch) {
                int ai = poslist[j];
                int pi = poslist[n_anch + j];
                float2 a2 = embb[ai * 64 + lane];
                float2 p2 = embb[pi * 64 + lane];
                float na_ = a2.x * a2.x + a2.y * a2.y;
                float np_ = p2.x * p2.x + p2.y * p2.y;
                float dp  = a2.x * p2.x + a2.y * p2.y;
                for (int off = 32; off; off >>= 1) {
                    na_ += __shfl_xor(na_, off, 64);
                    np_ += __shfl_xor(np_, off, 64);
                    dp  += __shfl_xor(dp,  off, 64);
                }
                float rna = 1.0f / fmaxf(sqrtf(na_), 1e-12f);
                float rnp = 1.0f / fmaxf(sqrtf(np_), 1e-12f);
                anchors[j][2 * lane]     = a2.x * rna;
                anchors[j][2 * lane + 1] = a2.y * rna;
                if (lane == 0) possim[j] = dp * rna * rnp * (1.0f / TAU);
            } else {
                anchors[j][2 * lane]     = 0.0f;
                anchors[j][2 * lane + 1] = 0.0f;
                if (lane == 0) possim[j] = 0.0f;
            }
        }
        __syncthreads();

        float part[8];
        #pragma unroll
        for (int j = 0; j < 8; ++j) part[j] = 0.0f;

        for (int i = 0; i < 4; ++i) {
            int g = tid + i * 256;
            if (g < 4 * SS) {
                int ol = g / SS;
                int s  = g - ol * SS;
                int o  = (ol >= b) ? ol + 1 : ol;
                int idx = o * SS + s;
                if (amask[idx] == 1 && pids[idx] > 0) {
                    const float4* nb = (const float4*)(emb + (size_t)idx * DD);
                    float acc[8];
                    float n2 = 0.0f;
                    #pragma unroll
                    for (int j = 0; j < 8; ++j) acc[j] = 0.0f;
                    #pragma unroll 8
                    for (int c = 0; c < DD / 4; ++c) {
                        float4 x = nb[c];
                        n2 += x.x * x.x + x.y * x.y + x.z * x.z + x.w * x.w;
                        #pragma unroll
                        for (int j = 0; j < 8; ++j) {
                            float4 a = ((const float4*)anchors[j])[c];
                            acc[j] += a.x * x.x + a.y * x.y + a.z * x.z + a.w * x.w;
                        }
                    }
                    float rn = 1.0f / fmaxf(sqrtf(n2), 1e-12f);
                    #pragma unroll
                    for (int j = 0; j < 8; ++j) {
                        float sim = acc[j] * rn * (1.0f / TAU);
                        part[j] += exp2f(sim * LOG2E);   // |sim|<=14.3: safe
                    }
                }
            }
        }

        #pragma unroll
        for (int j = 0; j < 8; ++j)
            for (int off = 32; off; off >>= 1)
                part[j] += __shfl_xor(part[j], off, 64);
        if (lane == 0) {
            #pragma unroll
            for (int j = 0; j < 8; ++j) red[wave][j] = part[j];
        }
        __syncthreads();

        if (tid < 8) {
            int j = tid;
            float ps = possim[j];
            float S  = exp2f(ps * LOG2E) + red[0][j] + red[1][j] + red[2][j] + red[3][j];
            float lse = log2f(S) * LN2;
            contrib_sh[j] = (j < n_anch) ? (lse - ps) : 0.0f;
        }
        __syncthreads();
        if (tid == 0) {
            float lb = 0.0f;
            for (int j = 0; j < 8; ++j) lb += contrib_sh[j];
            atomicAdd(&ws[2], lb);
            atomicAdd(&ws[3], (float)n_anch);
        }
    }
}

__global__ void finalize_kernel(const float* __restrict__ ws, float* __restrict__ out) {
    if (threadIdx.x == 0) {
        float fs = ws[0], vc = ws[1], cs = ws[2], pr = ws[3];
        float focal = vc > 0.0f ? fs / vc : 0.0f;
        float contr = pr > 0.0f ? cs / pr : 0.0f;
        out[0] = 0.6f * focal + 0.2f * contr;
    }
}

extern "C" void kernel_launch(void* const* d_in, const int* in_sizes, int n_in,
                              void* d_out, int out_size, void* d_ws, size_t ws_size,
                              hipStream_t stream) {
    const float* logits  = (const float*)d_in[0];
    const int*   targets = (const int*)d_in[1];
    const int*   mmask   = (const int*)d_in[2];
    const float* emb     = (const float*)d_in[3];
    const int*   pids    = (const int*)d_in[4];
    const int*   amask   = (const int*)d_in[5];
    float* out = (float*)d_out;
    float* ws  = (float*)d_ws;

    hipLaunchKernelGGL(init_ws_kernel, dim3(1), dim3(64), 0, stream, ws);
    hipLaunchKernelGGL(fused_loss_kernel, dim3(2048 + 64), dim3(256), 0, stream,
                       logits, targets, mmask, emb, pids, amask, ws);
    hipLaunchKernelGGL(finalize_kernel, dim3(1), dim3(64), 0, stream, ws, out);
}

// Round 3
// 279.497 us; speedup vs baseline: 1.1191x; 1.1191x over previous
//
#include <hip/hip_runtime.h>

#define V 5003
#define BB 64
#define SS 200
#define DD 128
#define TAU 0.07f
#define LOG2E 1.4426950408889634f
#define LN2 0.6931471805599453f
#define SHIFT 8.0f   // lse = SHIFT + log(sum exp(x - SHIFT)); exact, overflow-proof for |x|<80

// ws layout (floats):
//   [0      .. 2048)  focal partial sums   (one per focal block)
//   [2048   .. 4096)  focal valid counts   (as float)
//   [4096   .. 4160)  contrastive loss per batch
//   [4160   .. 4224)  contrastive n_anch per batch (as float)
#define WS_FS 0
#define WS_VC 2048
#define WS_CS 4096
#define WS_PR 4160

__global__ __launch_bounds__(256) void fused_loss_kernel(
    const float* __restrict__ logits,   // [64,128,5003]
    const int*   __restrict__ targets,  // [64,128]
    const int*   __restrict__ mmask,    // [64,128]
    const float* __restrict__ emb,      // [64,200,128]
    const int*   __restrict__ pids,     // [64,200]
    const int*   __restrict__ amask,    // [64,200]
    float* __restrict__ ws)
{
    const int tid  = threadIdx.x;
    const int lane = tid & 63;
    const int wave = tid >> 6;

    __shared__ float fl_sh[4];
    __shared__ int   vc_sh[4];
    __shared__ __align__(16) float anchors[8][DD];
    __shared__ float possim[8];
    __shared__ unsigned char validb[SS];
    __shared__ short poslist[16];
    __shared__ int   n_sh;
    __shared__ int   nanch_sh;
    __shared__ float red[4][8];
    __shared__ float contrib_sh[8];

    if (blockIdx.x < 2048) {
        // ================= FOCAL: one wave per row, shifted sum-exp =================
        const int r = blockIdx.x * 4 + wave;
        const float* row = logits + (size_t)r * V;

        // alignment peel: row starts at element r*5003; (r*5003)%4 == (r*3)%4
        const int p = (4 - ((r * 3) & 3)) & 3;     // scalars before 16B alignment
        const int t = 3 - p;                        // tail scalars

        const float4* row4 = (const float4*)(row + p);
        const float C = -SHIFT * LOG2E;

        float s0 = 0.f, s1 = 0.f, s2 = 0.f, s3 = 0.f;

        // 1250 float4 per row: 19 full wave-iterations + 34-lane partial
        int i = lane;
        #pragma unroll 4
        for (int it = 0; it < 19; ++it, i += 64) {
            float4 x = row4[i];
            s0 += exp2f(fmaf(x.x, LOG2E, C));
            s1 += exp2f(fmaf(x.y, LOG2E, C));
            s2 += exp2f(fmaf(x.z, LOG2E, C));
            s3 += exp2f(fmaf(x.w, LOG2E, C));
        }
        if (i < 1250) {                 // lanes 0..33
            float4 x = row4[i];
            s0 += exp2f(fmaf(x.x, LOG2E, C));
            s1 += exp2f(fmaf(x.y, LOG2E, C));
            s2 += exp2f(fmaf(x.z, LOG2E, C));
            s3 += exp2f(fmaf(x.w, LOG2E, C));
        }
        if (lane < p)                   // head scalars
            s0 += exp2f(fmaf(row[lane], LOG2E, C));
        if (lane < t)                   // tail scalars
            s0 += exp2f(fmaf(row[p + 5000 + lane], LOG2E, C));

        float s = (s0 + s1) + (s2 + s3);
        for (int off = 32; off; off >>= 1)
            s += __shfl_xor(s, off, 64);

        if (lane == 0) {
            int tg  = targets[r];
            int mk  = mmask[r];
            bool valid = (tg != -100) && (mk == 1);
            int tc = tg < 0 ? 0 : tg;
            float xt  = row[tc];
            float lse = SHIFT + log2f(s) * LN2;
            float lp  = xt - lse;                // log p_t  (<= 0)
            float pt  = exp2f(lp * LOG2E);
            float om  = 1.0f - pt;
            fl_sh[wave] = valid ? (om * om * (-lp)) : 0.0f;
            vc_sh[wave] = valid ? 1 : 0;
        }
        __syncthreads();
        if (tid == 0) {
            float fs = fl_sh[0] + fl_sh[1] + fl_sh[2] + fl_sh[3];
            int   vc = vc_sh[0] + vc_sh[1] + vc_sh[2] + vc_sh[3];
            ws[WS_FS + blockIdx.x] = fs;          // plain stores: no atomics
            ws[WS_VC + blockIdx.x] = (float)vc;
        }
    } else {
        // ================= CONTRASTIVE: one block per batch =================
        const int b = blockIdx.x - 2048;

        if (tid == 0) n_sh = 0;
        __syncthreads();

        if (tid < SS) {
            int idx = b * SS + tid;
            bool v = (amask[idx] == 1) && (pids[idx] > 0);
            validb[tid] = v ? 1 : 0;
            if (v) atomicAdd(&n_sh, 1);           // LDS atomic — cheap, block-local
        }
        __syncthreads();

        if (tid == 0) {
            int cnt = 0;
            for (int s = 0; s < SS && cnt < 16; ++s)
                if (validb[s]) poslist[cnt++] = (short)s;
            for (; cnt < 16; ++cnt) poslist[cnt] = (short)(SS - 1);
            int n  = n_sh;
            int na = n / 2;
            if (na > 8) na = 8;
            nanch_sh = na;
        }
        __syncthreads();
        const int n_anch = nanch_sh;

        const float2* embb = (const float2*)(emb + (size_t)b * SS * DD);
        for (int jj = 0; jj < 2; ++jj) {
            int j = wave + jj * 4;
            if (j < n_anch) {
                int ai = poslist[j];
                int pi = poslist[n_anch + j];
                float2 a2 = embb[ai * 64 + lane];
                float2 p2 = embb[pi * 64 + lane];
                float na_ = a2.x * a2.x + a2.y * a2.y;
                float np_ = p2.x * p2.x + p2.y * p2.y;
                float dp  = a2.x * p2.x + a2.y * p2.y;
                for (int off = 32; off; off >>= 1) {
                    na_ += __shfl_xor(na_, off, 64);
                    np_ += __shfl_xor(np_, off, 64);
                    dp  += __shfl_xor(dp,  off, 64);
                }
                float rna = 1.0f / fmaxf(sqrtf(na_), 1e-12f);
                float rnp = 1.0f / fmaxf(sqrtf(np_), 1e-12f);
                anchors[j][2 * lane]     = a2.x * rna;
                anchors[j][2 * lane + 1] = a2.y * rna;
                if (lane == 0) possim[j] = dp * rna * rnp * (1.0f / TAU);
            } else {
                anchors[j][2 * lane]     = 0.0f;
                anchors[j][2 * lane + 1] = 0.0f;
                if (lane == 0) possim[j] = 0.0f;
            }
        }
        __syncthreads();

        float part[8];
        #pragma unroll
        for (int j = 0; j < 8; ++j) part[j] = 0.0f;

        for (int i = 0; i < 4; ++i) {
            int g = tid + i * 256;
            if (g < 4 * SS) {
                int ol = g / SS;
                int s  = g - ol * SS;
                int o  = (ol >= b) ? ol + 1 : ol;
                int idx = o * SS + s;
                if (amask[idx] == 1 && pids[idx] > 0) {
                    const float4* nb = (const float4*)(emb + (size_t)idx * DD);
                    float acc[8];
                    float n2 = 0.0f;
                    #pragma unroll
                    for (int j = 0; j < 8; ++j) acc[j] = 0.0f;
                    #pragma unroll 8
                    for (int c = 0; c < DD / 4; ++c) {
                        float4 x = nb[c];
                        n2 += x.x * x.x + x.y * x.y + x.z * x.z + x.w * x.w;
                        #pragma unroll
                        for (int j = 0; j < 8; ++j) {
                            float4 a = ((const float4*)anchors[j])[c];
                            acc[j] += a.x * x.x + a.y * x.y + a.z * x.z + a.w * x.w;
                        }
                    }
                    float rn = 1.0f / fmaxf(sqrtf(n2), 1e-12f);
                    #pragma unroll
                    for (int j = 0; j < 8; ++j) {
                        float sim = acc[j] * rn * (1.0f / TAU);
                        part[j] += exp2f(sim * LOG2E);   // |sim|<=14.3: safe
                    }
                }
            }
        }

        #pragma unroll
        for (int j = 0; j < 8; ++j)
            for (int off = 32; off; off >>= 1)
                part[j] += __shfl_xor(part[j], off, 64);
        if (lane == 0) {
            #pragma unroll
            for (int j = 0; j < 8; ++j) red[wave][j] = part[j];
        }
        __syncthreads();

        if (tid < 8) {
            int j = tid;
            float ps = possim[j];
            float S  = exp2f(ps * LOG2E) + red[0][j] + red[1][j] + red[2][j] + red[3][j];
            float lse = log2f(S) * LN2;
            contrib_sh[j] = (j < n_anch) ? (lse - ps) : 0.0f;
        }
        __syncthreads();
        if (tid == 0) {
            float lb = 0.0f;
            for (int j = 0; j < 8; ++j) lb += contrib_sh[j];
            ws[WS_CS + b] = lb;                   // plain stores: no atomics
            ws[WS_PR + b] = (float)n_anch;
        }
    }
}

__global__ __launch_bounds__(256) void finalize_kernel(
    const float* __restrict__ ws, float* __restrict__ out)
{
    const int tid  = threadIdx.x;
    const int lane = tid & 63;
    const int wave = tid >> 6;
    __shared__ float r_fs[4], r_vc[4], r_cs[4], r_pr[4];

    float fs = 0.f, vc = 0.f, cs = 0.f, pr = 0.f;
    #pragma unroll
    for (int i = 0; i < 8; ++i) {
        fs += ws[WS_FS + tid + i * 256];
        vc += ws[WS_VC + tid + i * 256];
    }
    if (tid < 64) {
        cs = ws[WS_CS + tid];
        pr = ws[WS_PR + tid];
    }
    for (int off = 32; off; off >>= 1) {
        fs += __shfl_xor(fs, off, 64);
        vc += __shfl_xor(vc, off, 64);
        cs += __shfl_xor(cs, off, 64);
        pr += __shfl_xor(pr, off, 64);
    }
    if (lane == 0) { r_fs[wave] = fs; r_vc[wave] = vc; r_cs[wave] = cs; r_pr[wave] = pr; }
    __syncthreads();
    if (tid == 0) {
        float FS = r_fs[0] + r_fs[1] + r_fs[2] + r_fs[3];
        float VC = r_vc[0] + r_vc[1] + r_vc[2] + r_vc[3];
        float CS = r_cs[0] + r_cs[1] + r_cs[2] + r_cs[3];
        float PR = r_pr[0] + r_pr[1] + r_pr[2] + r_pr[3];
        float focal = VC > 0.0f ? FS / VC : 0.0f;
        float contr = PR > 0.0f ? CS / PR : 0.0f;
        out[0] = 0.6f * focal + 0.2f * contr;
    }
}

extern "C" void kernel_launch(void* const* d_in, const int* in_sizes, int n_in,
                              void* d_out, int out_size, void* d_ws, size_t ws_size,
                              hipStream_t stream) {
    const float* logits  = (const float*)d_in[0];
    const int*   targets = (const int*)d_in[1];
    const int*   mmask   = (const int*)d_in[2];
    const float* emb     = (const float*)d_in[3];
    const int*   pids    = (const int*)d_in[4];
    const int*   amask   = (const int*)d_in[5];
    float* out = (float*)d_out;
    float* ws  = (float*)d_ws;

    hipLaunchKernelGGL(fused_loss_kernel, dim3(2048 + 64), dim3(256), 0, stream,
                       logits, targets, mmask, emb, pids, amask, ws);
    hipLaunchKernelGGL(finalize_kernel, dim3(1), dim3(256), 0, stream, ws, out);
}